// Round 1
// baseline (1107.592 us; speedup 1.0000x reference)
//
#include <hip/hip_runtime.h>
#include <cstdint>
#include <cstddef>

typedef unsigned short u16;
typedef __attribute__((ext_vector_type(8))) short bf16x8;
typedef __attribute__((ext_vector_type(4))) float f32x4;

#define DEV __device__ __forceinline__

DEV u16 f2bf(float f) {                 // f32 -> bf16 bits, RNE
  uint32_t b = __float_as_uint(f);
  b += 0x7fffu + ((b >> 16) & 1u);
  return (u16)(b >> 16);
}
DEV float bf2f(u16 u) { return __uint_as_float(((uint32_t)u) << 16); }

// ---------------------------------------------------------------------------
// LN1 + token-shift: xn = LN(x); sx = state[:,1] - xn; a1 = xn + sx*maa_x
// ---------------------------------------------------------------------------
__global__ __launch_bounds__(256) void k_ln_mix1(
    const float* __restrict__ x, const float* __restrict__ state,
    const int* __restrict__ ip,
    const float* __restrict__ lw, const float* __restrict__ lb,
    const float* __restrict__ mx,
    u16* __restrict__ xn_o, u16* __restrict__ sx_o, u16* __restrict__ a1_o) {
  int b = blockIdx.x, t = threadIdx.x;
  const float* xr = x + (size_t)b * 2048;
  float4 v0 = *(const float4*)(xr + t * 8);
  float4 v1 = *(const float4*)(xr + t * 8 + 4);
  float xv[8] = {v0.x, v0.y, v0.z, v0.w, v1.x, v1.y, v1.z, v1.w};
  float s1 = 0.f, s2 = 0.f;
#pragma unroll
  for (int j = 0; j < 8; ++j) { s1 += xv[j]; s2 += xv[j] * xv[j]; }
#pragma unroll
  for (int off = 32; off; off >>= 1) { s1 += __shfl_xor(s1, off); s2 += __shfl_xor(s2, off); }
  __shared__ float ls1[4], ls2[4];
  int w = t >> 6;
  if ((t & 63) == 0) { ls1[w] = s1; ls2[w] = s2; }
  __syncthreads();
  s1 = ls1[0] + ls1[1] + ls1[2] + ls1[3];
  s2 = ls2[0] + ls2[1] + ls2[2] + ls2[3];
  float mu = s1 * (1.0f / 2048.0f);
  float var = s2 * (1.0f / 2048.0f) - mu * mu;
  float rs = rsqrtf(var + 1e-5f);
  const float* st = state + ((size_t)b * 66 + (size_t)66 * ip[0] + 1) * 2048;
  int e0 = t * 8;
  uint4 xnp, sxp, a1p;
  u16* xnl = (u16*)&xnp; u16* sxl = (u16*)&sxp; u16* a1l = (u16*)&a1p;
#pragma unroll
  for (int j = 0; j < 8; ++j) {
    int e = e0 + j;
    float xn = (xv[j] - mu) * rs * lw[e] + lb[e];
    float sxv = st[e] - xn;
    xnl[j] = f2bf(xn); sxl[j] = f2bf(sxv); a1l[j] = f2bf(xn + sxv * mx[e]);
  }
  size_t o = (size_t)b * 2048 + e0;
  *(uint4*)(xn_o + o) = xnp;
  *(uint4*)(sx_o + o) = sxp;
  *(uint4*)(a1_o + o) = a1p;
}

// ---------------------------------------------------------------------------
// LN2 + ffn token-shift: xk2/xr2 from x1, state row 0
// ---------------------------------------------------------------------------
__global__ __launch_bounds__(256) void k_ln_mix2(
    const float* __restrict__ x1, const float* __restrict__ state,
    const int* __restrict__ ip,
    const float* __restrict__ lw, const float* __restrict__ lb,
    const float* __restrict__ mk, const float* __restrict__ mr,
    u16* __restrict__ xk_o, u16* __restrict__ xr_o) {
  int b = blockIdx.x, t = threadIdx.x;
  const float* xr = x1 + (size_t)b * 2048;
  float4 v0 = *(const float4*)(xr + t * 8);
  float4 v1 = *(const float4*)(xr + t * 8 + 4);
  float xv[8] = {v0.x, v0.y, v0.z, v0.w, v1.x, v1.y, v1.z, v1.w};
  float s1 = 0.f, s2 = 0.f;
#pragma unroll
  for (int j = 0; j < 8; ++j) { s1 += xv[j]; s2 += xv[j] * xv[j]; }
#pragma unroll
  for (int off = 32; off; off >>= 1) { s1 += __shfl_xor(s1, off); s2 += __shfl_xor(s2, off); }
  __shared__ float ls1[4], ls2[4];
  int w = t >> 6;
  if ((t & 63) == 0) { ls1[w] = s1; ls2[w] = s2; }
  __syncthreads();
  s1 = ls1[0] + ls1[1] + ls1[2] + ls1[3];
  s2 = ls2[0] + ls2[1] + ls2[2] + ls2[3];
  float mu = s1 * (1.0f / 2048.0f);
  float var = s2 * (1.0f / 2048.0f) - mu * mu;
  float rs = rsqrtf(var + 1e-5f);
  const float* st = state + ((size_t)b * 66 + (size_t)66 * ip[0] + 0) * 2048;
  int e0 = t * 8;
  uint4 xkp, xrp;
  u16* xkl = (u16*)&xkp; u16* xrl = (u16*)&xrp;
#pragma unroll
  for (int j = 0; j < 8; ++j) {
    int e = e0 + j;
    float xn = (xv[j] - mu) * rs * lw[e] + lb[e];
    float sxv = st[e] - xn;
    xkl[j] = f2bf(xn + sxv * mk[e]);
    xrl[j] = f2bf(xn + sxv * mr[e]);
  }
  size_t o = (size_t)b * 2048 + e0;
  *(uint4*)(xk_o + o) = xkp;
  *(uint4*)(xr_o + o) = xrp;
}

// ---------------------------------------------------------------------------
// Generic batched bf16 MFMA GEMM: C[M,N] = epilogue(A[M,K] @ op(B))
//   A: bf16 row-major, lda.  B: f32; bt=1 -> B[N,K] (W.T form), bt=0 -> B[K,N].
//   128x128 tile, BK=32, 256 threads (2x2 waves of 64x64), single-buffered.
// ---------------------------------------------------------------------------
enum { EP_STORE = 0, EP_SILU, EP_TANH, EP_MIX, EP_ADDX, EP_SIG, EP_RELU2, EP_FINAL };

struct GemmDesc {
  const u16* A; const float* B; void* C;
  const void* p1; const void* p2; const float* pvec;
  int lda, ldb, ldc, N, K, bt, ep;
};
struct GemmBatch { GemmDesc g[4]; int bpg; };

__global__ __launch_bounds__(256, 2) void k_gemm(GemmBatch bat) {
  int gi = blockIdx.x / bat.bpg;
  int bid = blockIdx.x % bat.bpg;
  GemmDesc g = bat.g[gi];
  int ntn = (g.N + 127) >> 7;
  int m0 = (bid / ntn) << 7;
  int n0 = (bid % ntn) << 7;
  __shared__ u16 As[128 * 32];
  __shared__ u16 Bs[128 * 32];   // Bs[n][k]
  int t = threadIdx.x, w = t >> 6, lane = t & 63;
  int wm = w >> 1, wn = w & 1;
  int lr = lane & 15, kb = (lane >> 4) * 8;
  f32x4 acc[4][4] = {};

  for (int k0 = 0; k0 < g.K; k0 += 32) {
    // stage A tile [128][32] bf16
#pragma unroll
    for (int inst = 0; inst < 2; ++inst) {
      int ee = t * 8 + inst * 2048;
      int row = ee >> 5, col = ee & 31;
      *(uint4*)(As + ee) = *(const uint4*)(g.A + (size_t)(m0 + row) * g.lda + k0 + col);
    }
    // stage B tile -> Bs[n][k], f32 -> bf16
    if (g.bt) {
#pragma unroll
      for (int it = 0; it < 4; ++it) {
        int idx = it * 256 + t;
        int n = idx >> 3, c4 = (idx & 7) * 4;
        float4 bv = *(const float4*)(g.B + (size_t)(n0 + n) * g.ldb + k0 + c4);
        u16* d = Bs + n * 32 + c4;
        d[0] = f2bf(bv.x); d[1] = f2bf(bv.y); d[2] = f2bf(bv.z); d[3] = f2bf(bv.w);
      }
    } else {
#pragma unroll
      for (int it = 0; it < 4; ++it) {
        int idx = it * 256 + t;
        int k = idx >> 5, c4 = (idx & 31) * 4;
        float4 bv = make_float4(0.f, 0.f, 0.f, 0.f);
        if (n0 + c4 < g.N)
          bv = *(const float4*)(g.B + (size_t)(k0 + k) * g.ldb + n0 + c4);
        Bs[(c4 + 0) * 32 + k] = f2bf(bv.x);
        Bs[(c4 + 1) * 32 + k] = f2bf(bv.y);
        Bs[(c4 + 2) * 32 + k] = f2bf(bv.z);
        Bs[(c4 + 3) * 32 + k] = f2bf(bv.w);
      }
    }
    __syncthreads();
    bf16x8 af[4], bf[4];
#pragma unroll
    for (int m = 0; m < 4; ++m)
      af[m] = *(const bf16x8*)(As + (wm * 64 + m * 16 + lr) * 32 + kb);
#pragma unroll
    for (int n = 0; n < 4; ++n)
      bf[n] = *(const bf16x8*)(Bs + (wn * 64 + n * 16 + lr) * 32 + kb);
#pragma unroll
    for (int m = 0; m < 4; ++m)
#pragma unroll
      for (int n = 0; n < 4; ++n)
        acc[m][n] = __builtin_amdgcn_mfma_f32_16x16x32_bf16(af[m], bf[n], acc[m][n], 0, 0, 0);
    __syncthreads();
  }

  // epilogue: D lane l reg q -> row=(l>>4)*4+q, col=l&15  [m89-verified mapping]
  int ep = g.ep;
#pragma unroll
  for (int m = 0; m < 4; ++m) {
    int grow0 = m0 + wm * 64 + m * 16 + (lane >> 4) * 4;
#pragma unroll
    for (int n = 0; n < 4; ++n) {
      int gc = n0 + wn * 64 + n * 16 + lr;
      if (gc >= g.N) continue;
#pragma unroll
      for (int q = 0; q < 4; ++q) {
        size_t ci = (size_t)(grow0 + q) * g.ldc + gc;
        float v = acc[m][n][q];
        switch (ep) {
          case EP_STORE: ((u16*)g.C)[ci] = f2bf(v); break;
          case EP_SILU:  ((u16*)g.C)[ci] = f2bf(v / (1.f + __expf(-v))); break;
          case EP_TANH:  ((u16*)g.C)[ci] = f2bf(tanhf(v)); break;
          case EP_MIX: {
            float xn = bf2f(((const u16*)g.p1)[ci]);
            float sxv = bf2f(((const u16*)g.p2)[ci]);
            ((u16*)g.C)[ci] = f2bf(xn + sxv * (g.pvec[gc] + v));
          } break;
          case EP_ADDX: ((float*)g.C)[ci] = ((const float*)g.p1)[ci] + v; break;
          case EP_SIG:  ((u16*)g.C)[ci] = f2bf(1.f / (1.f + __expf(-v))); break;
          case EP_RELU2: { float r = v > 0.f ? v : 0.f; ((u16*)g.C)[ci] = f2bf(r * r); } break;
          case EP_FINAL:
            ((float*)g.C)[ci] = ((const float*)g.p1)[ci] +
                                bf2f(((const u16*)g.p2)[ci]) * v;
            break;
        }
      }
    }
  }
}

// ---------------------------------------------------------------------------
// WKV readout + groupnorm + silu-gate. One wave per (b,h).
// y_j = (sum_i r_i f_i k_i) v_j + sum_i r_i s[b,h,i,j]
// s[b,h,i,j] = state[b, 66*i_in + 2 + 2h + (i>>5), (i&31)*64 + j]
// t = (GN(y)*gn_w + gn_b) * g
// ---------------------------------------------------------------------------
__global__ __launch_bounds__(256) void k_wkv(
    const u16* __restrict__ rb, const u16* __restrict__ kbuf,
    const u16* __restrict__ vb, const u16* __restrict__ gb,
    const float* __restrict__ state, const int* __restrict__ ip,
    const float* __restrict__ fa, const float* __restrict__ gw,
    const float* __restrict__ gbias, u16* __restrict__ t_o) {
  int t = threadIdx.x, w = t >> 6, lane = t & 63;
  int flat = blockIdx.x * 4 + w;
  int b = flat >> 5, h = flat & 31;
  int base = (b << 11) + (h << 6);
  float r  = bf2f(rb[base + lane]);
  float kv = bf2f(kbuf[base + lane]);
  float vv = bf2f(vb[base + lane]);
  float f  = fa[(h << 6) + lane];
  __shared__ float rs[4][64];
  rs[w][lane] = r;
  __syncthreads();
  float c = r * f * kv;
#pragma unroll
  for (int off = 32; off; off >>= 1) c += __shfl_xor(c, off);

  const float* sp = state + ((size_t)b * 66 + (size_t)66 * ip[0] + 2 + 2 * h) * 2048;
  int q = lane >> 4, jj = lane & 15;
  float yp0 = 0.f, yp1 = 0.f, yp2 = 0.f, yp3 = 0.f;
#pragma unroll
  for (int ib = 0; ib < 16; ++ib) {
    int i = ib * 4 + q;
    float4 sv = *(const float4*)(sp + ((i >> 5) * 2048) + ((i & 31) << 6) + jj * 4);
    float ri = rs[w][i];
    yp0 += ri * sv.x; yp1 += ri * sv.y; yp2 += ri * sv.z; yp3 += ri * sv.w;
  }
#pragma unroll
  for (int off = 16; off <= 32; off <<= 1) {
    yp0 += __shfl_xor(yp0, off); yp1 += __shfl_xor(yp1, off);
    yp2 += __shfl_xor(yp2, off); yp3 += __shfl_xor(yp3, off);
  }
  // lane j collects component (j&3) from lane (j>>2)
  int src = lane >> 2, cc = lane & 3;
  float t0 = __shfl(yp0, src), t1 = __shfl(yp1, src);
  float t2 = __shfl(yp2, src), t3 = __shfl(yp3, src);
  float y = cc == 0 ? t0 : cc == 1 ? t1 : cc == 2 ? t2 : t3;
  y += c * vv;
  // groupnorm over the 64 lanes (= one head)
  float s1 = y, s2 = y * y;
#pragma unroll
  for (int off = 32; off; off >>= 1) { s1 += __shfl_xor(s1, off); s2 += __shfl_xor(s2, off); }
  float mu = s1 * (1.f / 64.f);
  float var = s2 * (1.f / 64.f) - mu * mu;
  float yn = (y - mu) * rsqrtf(var + 1e-5f);
  float tg = (yn * gw[(h << 6) + lane] + gbias[(h << 6) + lane]) * bf2f(gb[base + lane]);
  t_o[base + lane] = f2bf(tg);
}

// ---------------------------------------------------------------------------
extern "C" void kernel_launch(void* const* d_in, const int* in_sizes, int n_in,
                              void* d_out, int out_size, void* d_ws, size_t ws_size,
                              hipStream_t stream) {
  const float* x      = (const float*)d_in[0];
  const float* state  = (const float*)d_in[1];
  const float* ln1_w  = (const float*)d_in[2];
  const float* ln1_b  = (const float*)d_in[3];
  const float* ln2_w  = (const float*)d_in[4];
  const float* ln2_b  = (const float*)d_in[5];
  const float* maa_x  = (const float*)d_in[6];
  const float* maa_k  = (const float*)d_in[8];
  const float* maa_v  = (const float*)d_in[9];
  const float* maa_r  = (const float*)d_in[10];
  const float* maa_g  = (const float*)d_in[11];
  const float* maa_w1 = (const float*)d_in[12];
  const float* maa_w2 = (const float*)d_in[13];
  // decay (14,15,16) are dead code: w gate never reaches the returned output
  const float* faaaa  = (const float*)d_in[17];
  const float* Wr     = (const float*)d_in[18];
  const float* Wk     = (const float*)d_in[19];
  const float* Wv     = (const float*)d_in[20];
  const float* Wo     = (const float*)d_in[21];
  const float* Wg     = (const float*)d_in[22];
  const float* gn_w   = (const float*)d_in[23];
  const float* gn_b   = (const float*)d_in[24];
  const float* fmk    = (const float*)d_in[25];
  const float* fmr    = (const float*)d_in[26];
  const float* fWk    = (const float*)d_in[27];
  const float* fWr    = (const float*)d_in[28];
  const float* fWv    = (const float*)d_in[29];
  const int*   ip     = (const int*)d_in[30];
  float* out = (float*)d_out;

  char* wsb = (char*)d_ws;
  const size_t MB = 1ull << 20;
  u16* xn  = (u16*)(wsb + 0 * MB);    // [1024,2048] bf16
  u16* sx  = (u16*)(wsb + 4 * MB);
  u16* a1  = (u16*)(wsb + 8 * MB);
  u16* xxx = (u16*)(wsb + 12 * MB);   // [1024,320]
  u16* xk  = (u16*)(wsb + 13 * MB);
  u16* xv  = (u16*)(wsb + 17 * MB);
  u16* xr  = (u16*)(wsb + 21 * MB);
  u16* xg  = (u16*)(wsb + 25 * MB);
  u16* rb  = (u16*)(wsb + 29 * MB);
  u16* kb  = (u16*)(wsb + 33 * MB);
  u16* vbf = (u16*)(wsb + 37 * MB);
  u16* gbf = (u16*)(wsb + 41 * MB);
  u16* tb  = (u16*)(wsb + 45 * MB);
  float* x1 = (float*)(wsb + 49 * MB); // [1024,2048] f32
  u16* xk2 = (u16*)(wsb + 57 * MB);
  u16* xr2 = (u16*)(wsb + 61 * MB);
  u16* rr  = (u16*)(wsb + 65 * MB);
  u16* kkb = (u16*)(wsb + 69 * MB);   // 73 MB total

  auto mkd = [](const u16* A, const float* B, void* C, const void* p1,
                const void* p2, const float* pvec, int lda, int ldb, int ldc,
                int N, int K, int btf, int epf) {
    GemmDesc d; d.A = A; d.B = B; d.C = C; d.p1 = p1; d.p2 = p2; d.pvec = pvec;
    d.lda = lda; d.ldb = ldb; d.ldc = ldc; d.N = N; d.K = K; d.bt = btf; d.ep = epf;
    return d;
  };

  // 1) LN1 + shift
  k_ln_mix1<<<1024, 256, 0, stream>>>(x, state, ip, ln1_w, ln1_b, maa_x, xn, sx, a1);

  // 2) xxx = tanh(a1 @ maa_w1)   [1024,320]
  {
    GemmBatch g{}; g.bpg = 8 * 3;
    g.g[0] = mkd(a1, maa_w1, xxx, nullptr, nullptr, nullptr, 2048, 320, 320, 320, 2048, 0, EP_TANH);
    k_gemm<<<24, 256, 0, stream>>>(g);
  }

  // 3) LoRA mix j=1..4: x* = xn + sx*(maa_* + xxx_j @ maa_w2[j])  (j=0 dead)
  {
    GemmBatch g{}; g.bpg = 8 * 16;
    const float* mv[4] = {maa_k, maa_v, maa_r, maa_g};
    u16* tv[4] = {xk, xv, xr, xg};
    for (int j = 1; j <= 4; ++j)
      g.g[j - 1] = mkd(xxx + j * 64, maa_w2 + (size_t)j * 64 * 2048, tv[j - 1],
                       xn, sx, mv[j - 1], 320, 2048, 2048, 2048, 64, 0, EP_MIX);
    k_gemm<<<512, 256, 0, stream>>>(g);
  }

  // 4) r,k,v,g big GEMMs (batched for occupancy: 512 blocks)
  {
    GemmBatch g{}; g.bpg = 8 * 16;
    g.g[0] = mkd(xr, Wr, rb,  nullptr, nullptr, nullptr, 2048, 2048, 2048, 2048, 2048, 1, EP_STORE);
    g.g[1] = mkd(xk, Wk, kb,  nullptr, nullptr, nullptr, 2048, 2048, 2048, 2048, 2048, 1, EP_STORE);
    g.g[2] = mkd(xv, Wv, vbf, nullptr, nullptr, nullptr, 2048, 2048, 2048, 2048, 2048, 1, EP_STORE);
    g.g[3] = mkd(xg, Wg, gbf, nullptr, nullptr, nullptr, 2048, 2048, 2048, 2048, 2048, 1, EP_SILU);
    k_gemm<<<512, 256, 0, stream>>>(g);
  }

  // 5) WKV + groupnorm + gate
  k_wkv<<<8192, 256, 0, stream>>>(rb, kb, vbf, gbf, state, ip, faaaa, gn_w, gn_b, tb);

  // 6) x1 = x + t @ Wo.T
  {
    GemmBatch g{}; g.bpg = 8 * 16;
    g.g[0] = mkd(tb, Wo, x1, x, nullptr, nullptr, 2048, 2048, 2048, 2048, 2048, 1, EP_ADDX);
    k_gemm<<<128, 256, 0, stream>>>(g);
  }

  // 7) LN2 + ffn shift
  k_ln_mix2<<<1024, 256, 0, stream>>>(x1, state, ip, ln2_w, ln2_b, fmk, fmr, xk2, xr2);

  // 8) rr = sigmoid(xr2@ffn_Wr.T); kk = relu(xk2@ffn_Wk.T)^2
  {
    GemmBatch g{}; g.bpg = 8 * 16;
    g.g[0] = mkd(xr2, fWr, rr,  nullptr, nullptr, nullptr, 2048, 2048, 2048, 2048, 2048, 1, EP_SIG);
    g.g[1] = mkd(xk2, fWk, kkb, nullptr, nullptr, nullptr, 2048, 2048, 2048, 2048, 2048, 1, EP_RELU2);
    k_gemm<<<256, 256, 0, stream>>>(g);
  }

  // 9) out = x1 + rr * (kk @ ffn_Wv.T)
  {
    GemmBatch g{}; g.bpg = 8 * 16;
    g.g[0] = mkd(kkb, fWv, out, x1, rr, nullptr, 2048, 2048, 2048, 2048, 2048, 1, EP_FINAL);
    k_gemm<<<128, 256, 0, stream>>>(g);
  }
}

// Round 2
// 415.094 us; speedup vs baseline: 2.6683x; 2.6683x over previous
//
#include <hip/hip_runtime.h>
#include <cstdint>
#include <cstddef>

typedef unsigned short u16;
typedef __attribute__((ext_vector_type(8))) short bf16x8;
typedef __attribute__((ext_vector_type(4))) float f32x4;

#define DEV __device__ __forceinline__

DEV u16 f2bf(float f) {                 // f32 -> bf16 bits, RNE
  uint32_t b = __float_as_uint(f);
  b += 0x7fffu + ((b >> 16) & 1u);
  return (u16)(b >> 16);
}
DEV float bf2f(u16 u) { return __uint_as_float(((uint32_t)u) << 16); }

DEV void gl16(const u16* g, u16* l) {   // async global->LDS, 16B/lane, dest = base + lane*16
  __builtin_amdgcn_global_load_lds(
      (const __attribute__((address_space(1))) void*)g,
      (__attribute__((address_space(3))) void*)l, 16, 0, 0);
}

// ---------------------------------------------------------------------------
// Weight f32 -> bf16 bulk convert: 8 square [2048,2048] weights
// ---------------------------------------------------------------------------
struct CvtArgs { const float* s[8]; };

__global__ __launch_bounds__(256) void k_cvt8(CvtArgs a, u16* __restrict__ dst) {
  size_t idx = ((size_t)blockIdx.x * 256 + threadIdx.x) * 8;
  int w = (int)(idx >> 22);
  size_t off = idx & ((1u << 22) - 1);
  const float* s = a.s[w];
  float4 v0 = *(const float4*)(s + off);
  float4 v1 = *(const float4*)(s + off + 4);
  uint4 p; u16* pl = (u16*)&p;
  pl[0] = f2bf(v0.x); pl[1] = f2bf(v0.y); pl[2] = f2bf(v0.z); pl[3] = f2bf(v0.w);
  pl[4] = f2bf(v1.x); pl[5] = f2bf(v1.y); pl[6] = f2bf(v1.z); pl[7] = f2bf(v1.w);
  *(uint4*)(dst + ((size_t)w << 22) + off) = p;
}

// transpose-convert maa_w1 [2048,320] -> w1t[320][2048]; maa_w2[1..4][64][2048] -> w2t[4][2048][64]
__global__ __launch_bounds__(256) void k_cvtT(const float* __restrict__ w1,
                                              const float* __restrict__ w2,
                                              u16* __restrict__ w1t, u16* __restrict__ w2t) {
  int idx = blockIdx.x * 256 + threadIdx.x;
  if (idx < 655360) {
    int n = idx >> 11, k = idx & 2047;
    w1t[idx] = f2bf(w1[(size_t)k * 320 + n]);
  } else {
    int r = idx - 655360;              // < 524288
    int j = r >> 17, q = r & 131071;
    int n = q >> 6, k2 = q & 63;
    w2t[r] = f2bf(w2[((size_t)(j + 1) * 64 + k2) * 2048 + n]);
  }
}

__global__ __launch_bounds__(256) void k_tanhpack(const float* __restrict__ xf,
                                                  u16* __restrict__ xb) {
  int idx = blockIdx.x * 256 + threadIdx.x;   // 327680 total
  xb[idx] = f2bf(tanhf(xf[idx]));
}

// ---------------------------------------------------------------------------
// LN1 + token-shift (+ zero xxxf accumulator)
// ---------------------------------------------------------------------------
__global__ __launch_bounds__(256) void k_ln_mix1(
    const float* __restrict__ x, const float* __restrict__ state,
    const int* __restrict__ ip,
    const float* __restrict__ lw, const float* __restrict__ lb,
    const float* __restrict__ mx,
    u16* __restrict__ xn_o, u16* __restrict__ sx_o, u16* __restrict__ a1_o,
    float* __restrict__ xxxf) {
  int b = blockIdx.x, t = threadIdx.x;
  float* zf = xxxf + (size_t)b * 320;
  zf[t] = 0.f;
  if (t < 64) zf[256 + t] = 0.f;
  const float* xr = x + (size_t)b * 2048;
  float4 v0 = *(const float4*)(xr + t * 8);
  float4 v1 = *(const float4*)(xr + t * 8 + 4);
  float xv[8] = {v0.x, v0.y, v0.z, v0.w, v1.x, v1.y, v1.z, v1.w};
  float s1 = 0.f, s2 = 0.f;
#pragma unroll
  for (int j = 0; j < 8; ++j) { s1 += xv[j]; s2 += xv[j] * xv[j]; }
#pragma unroll
  for (int off = 32; off; off >>= 1) { s1 += __shfl_xor(s1, off); s2 += __shfl_xor(s2, off); }
  __shared__ float ls1[4], ls2[4];
  int w = t >> 6;
  if ((t & 63) == 0) { ls1[w] = s1; ls2[w] = s2; }
  __syncthreads();
  s1 = ls1[0] + ls1[1] + ls1[2] + ls1[3];
  s2 = ls2[0] + ls2[1] + ls2[2] + ls2[3];
  float mu = s1 * (1.0f / 2048.0f);
  float var = s2 * (1.0f / 2048.0f) - mu * mu;
  float rs = rsqrtf(var + 1e-5f);
  const float* st = state + ((size_t)b * 66 + (size_t)66 * ip[0] + 1) * 2048;
  int e0 = t * 8;
  uint4 xnp, sxp, a1p;
  u16* xnl = (u16*)&xnp; u16* sxl = (u16*)&sxp; u16* a1l = (u16*)&a1p;
#pragma unroll
  for (int j = 0; j < 8; ++j) {
    int e = e0 + j;
    float xn = (xv[j] - mu) * rs * lw[e] + lb[e];
    float sxv = st[e] - xn;
    xnl[j] = f2bf(xn); sxl[j] = f2bf(sxv); a1l[j] = f2bf(xn + sxv * mx[e]);
  }
  size_t o = (size_t)b * 2048 + e0;
  *(uint4*)(xn_o + o) = xnp;
  *(uint4*)(sx_o + o) = sxp;
  *(uint4*)(a1_o + o) = a1p;
}

// ---------------------------------------------------------------------------
// LN2 + ffn token-shift (+ out = x1 residual init)
// ---------------------------------------------------------------------------
__global__ __launch_bounds__(256) void k_ln_mix2(
    const float* __restrict__ x1, const float* __restrict__ state,
    const int* __restrict__ ip,
    const float* __restrict__ lw, const float* __restrict__ lb,
    const float* __restrict__ mk, const float* __restrict__ mr,
    u16* __restrict__ xk_o, u16* __restrict__ xr_o, float* __restrict__ out) {
  int b = blockIdx.x, t = threadIdx.x;
  const float* xr = x1 + (size_t)b * 2048;
  float4 v0 = *(const float4*)(xr + t * 8);
  float4 v1 = *(const float4*)(xr + t * 8 + 4);
  float* op = out + (size_t)b * 2048 + t * 8;
  *(float4*)op = v0;
  *(float4*)(op + 4) = v1;
  float xv[8] = {v0.x, v0.y, v0.z, v0.w, v1.x, v1.y, v1.z, v1.w};
  float s1 = 0.f, s2 = 0.f;
#pragma unroll
  for (int j = 0; j < 8; ++j) { s1 += xv[j]; s2 += xv[j] * xv[j]; }
#pragma unroll
  for (int off = 32; off; off >>= 1) { s1 += __shfl_xor(s1, off); s2 += __shfl_xor(s2, off); }
  __shared__ float ls1[4], ls2[4];
  int w = t >> 6;
  if ((t & 63) == 0) { ls1[w] = s1; ls2[w] = s2; }
  __syncthreads();
  s1 = ls1[0] + ls1[1] + ls1[2] + ls1[3];
  s2 = ls2[0] + ls2[1] + ls2[2] + ls2[3];
  float mu = s1 * (1.0f / 2048.0f);
  float var = s2 * (1.0f / 2048.0f) - mu * mu;
  float rs = rsqrtf(var + 1e-5f);
  const float* st = state + ((size_t)b * 66 + (size_t)66 * ip[0] + 0) * 2048;
  int e0 = t * 8;
  uint4 xkp, xrp;
  u16* xkl = (u16*)&xkp; u16* xrl = (u16*)&xrp;
#pragma unroll
  for (int j = 0; j < 8; ++j) {
    int e = e0 + j;
    float xn = (xv[j] - mu) * rs * lw[e] + lb[e];
    float sxv = st[e] - xn;
    xkl[j] = f2bf(xn + sxv * mk[e]);
    xrl[j] = f2bf(xn + sxv * mr[e]);
  }
  size_t o = (size_t)b * 2048 + e0;
  *(uint4*)(xk_o + o) = xkp;
  *(uint4*)(xr_o + o) = xrp;
}

// ---------------------------------------------------------------------------
// Generic batched bf16 MFMA GEMM (m97 structure): C[M,N] = ep(A[M,K] @ B[N,K]^T)
//   A,B bf16 row-major (K contiguous). 128x128 tile, BK=32, 4 waves,
//   global_load_lds 16B staging, single-buffered.
// ---------------------------------------------------------------------------
enum { EP_STORE = 0, EP_SILU, EP_MIX, EP_SIG, EP_RELU2, EP_AT, EP_ATSC };

struct GemmDesc {
  const u16* A; const u16* B; void* C;
  const void* p1; const void* p2; const float* pvec;
  int lda, ldb, ldc, N, K, k0, ep;
};
struct GemmBatch { GemmDesc g[4]; int bpg; };

__global__ __launch_bounds__(256, 2) void k_gemm(GemmBatch bat) {
  int gi = blockIdx.x / bat.bpg;
  int bid = blockIdx.x % bat.bpg;
  GemmDesc g = bat.g[gi];
  int ntn = (g.N + 127) >> 7;
  int m0 = (bid / ntn) << 7;
  int n0 = (bid % ntn) << 7;
  __shared__ u16 As[128 * 32];
  __shared__ u16 Bs[128 * 32];
  int t = threadIdx.x, w = t >> 6, lane = t & 63;
  int wm = w >> 1, wn = w & 1;
  int lr = lane & 15, kb = (lane >> 4) * 8;
  // per-lane global staging bases: wave w covers rows [w*32, w*32+32)
  const u16* Ab = g.A + (size_t)(m0 + w * 32 + (lane >> 2)) * g.lda + (lane & 3) * 8;
  const u16* Bb = g.B + (size_t)(n0 + w * 32 + (lane >> 2)) * g.ldb + (lane & 3) * 8;
  u16* Al0 = As + (w * 32) * 32;
  u16* Al1 = As + (w * 32 + 16) * 32;
  u16* Bl0 = Bs + (w * 32) * 32;
  u16* Bl1 = Bs + (w * 32 + 16) * 32;
  int a16 = 16 * g.lda, b16 = 16 * g.ldb;
  f32x4 acc[4][4] = {};

  int kend = g.k0 + g.K;
  for (int k0 = g.k0; k0 < kend; k0 += 32) {
    gl16(Ab + k0, Al0);
    gl16(Ab + k0 + a16, Al1);
    gl16(Bb + k0, Bl0);
    gl16(Bb + k0 + b16, Bl1);
    __syncthreads();
    bf16x8 af[4], bfr[4];
#pragma unroll
    for (int m = 0; m < 4; ++m)
      af[m] = *(const bf16x8*)(As + (wm * 64 + m * 16 + lr) * 32 + kb);
#pragma unroll
    for (int n = 0; n < 4; ++n)
      bfr[n] = *(const bf16x8*)(Bs + (wn * 64 + n * 16 + lr) * 32 + kb);
#pragma unroll
    for (int m = 0; m < 4; ++m)
#pragma unroll
      for (int n = 0; n < 4; ++n)
        acc[m][n] = __builtin_amdgcn_mfma_f32_16x16x32_bf16(af[m], bfr[n], acc[m][n], 0, 0, 0);
    __syncthreads();
  }

  // epilogue: D lane l reg q -> row=(l>>4)*4+q, col=l&15
  int ep = g.ep;
#pragma unroll
  for (int m = 0; m < 4; ++m) {
    int grow0 = m0 + wm * 64 + m * 16 + (lane >> 4) * 4;
#pragma unroll
    for (int n = 0; n < 4; ++n) {
      int gc = n0 + wn * 64 + n * 16 + lr;
      if (gc >= g.N) continue;
#pragma unroll
      for (int q = 0; q < 4; ++q) {
        size_t ci = (size_t)(grow0 + q) * g.ldc + gc;
        float v = acc[m][n][q];
        switch (ep) {
          case EP_STORE: ((u16*)g.C)[ci] = f2bf(v); break;
          case EP_SILU:  ((u16*)g.C)[ci] = f2bf(v / (1.f + __expf(-v))); break;
          case EP_MIX: {
            float xn = bf2f(((const u16*)g.p1)[ci]);
            float sxv = bf2f(((const u16*)g.p2)[ci]);
            ((u16*)g.C)[ci] = f2bf(xn + sxv * (g.pvec[gc] + v));
          } break;
          case EP_SIG:  ((u16*)g.C)[ci] = f2bf(1.f / (1.f + __expf(-v))); break;
          case EP_RELU2: { float r = v > 0.f ? v : 0.f; ((u16*)g.C)[ci] = f2bf(r * r); } break;
          case EP_AT:   atomicAdd((float*)g.C + ci, v); break;
          case EP_ATSC: atomicAdd((float*)g.C + ci, bf2f(((const u16*)g.p2)[ci]) * v); break;
        }
      }
    }
  }
}

// ---------------------------------------------------------------------------
// WKV readout + groupnorm + silu-gate (+ x1 = x residual init). One wave per (b,h).
// ---------------------------------------------------------------------------
__global__ __launch_bounds__(256) void k_wkv(
    const u16* __restrict__ rb, const u16* __restrict__ kbuf,
    const u16* __restrict__ vb, const u16* __restrict__ gb,
    const float* __restrict__ state, const int* __restrict__ ip,
    const float* __restrict__ fa, const float* __restrict__ gw,
    const float* __restrict__ gbias, u16* __restrict__ t_o,
    const float* __restrict__ x, float* __restrict__ x1) {
  int t = threadIdx.x, w = t >> 6, lane = t & 63;
  int flat = blockIdx.x * 4 + w;
  int b = flat >> 5, h = flat & 31;
  int base = (b << 11) + (h << 6);
  x1[base + lane] = x[base + lane];
  float r  = bf2f(rb[base + lane]);
  float kv = bf2f(kbuf[base + lane]);
  float vv = bf2f(vb[base + lane]);
  float f  = fa[(h << 6) + lane];
  __shared__ float rs[4][64];
  rs[w][lane] = r;
  __syncthreads();
  float c = r * f * kv;
#pragma unroll
  for (int off = 32; off; off >>= 1) c += __shfl_xor(c, off);

  const float* sp = state + ((size_t)b * 66 + (size_t)66 * ip[0] + 2 + 2 * h) * 2048;
  int q = lane >> 4, jj = lane & 15;
  float yp0 = 0.f, yp1 = 0.f, yp2 = 0.f, yp3 = 0.f;
#pragma unroll
  for (int ib = 0; ib < 16; ++ib) {
    int i = ib * 4 + q;
    float4 sv = *(const float4*)(sp + ((i >> 5) * 2048) + ((i & 31) << 6) + jj * 4);
    float ri = rs[w][i];
    yp0 += ri * sv.x; yp1 += ri * sv.y; yp2 += ri * sv.z; yp3 += ri * sv.w;
  }
#pragma unroll
  for (int off = 16; off <= 32; off <<= 1) {
    yp0 += __shfl_xor(yp0, off); yp1 += __shfl_xor(yp1, off);
    yp2 += __shfl_xor(yp2, off); yp3 += __shfl_xor(yp3, off);
  }
  int src = lane >> 2, cc = lane & 3;
  float t0 = __shfl(yp0, src), t1 = __shfl(yp1, src);
  float t2 = __shfl(yp2, src), t3 = __shfl(yp3, src);
  float y = cc == 0 ? t0 : cc == 1 ? t1 : cc == 2 ? t2 : t3;
  y += c * vv;
  float s1 = y, s2 = y * y;
#pragma unroll
  for (int off = 32; off; off >>= 1) { s1 += __shfl_xor(s1, off); s2 += __shfl_xor(s2, off); }
  float mu = s1 * (1.f / 64.f);
  float var = s2 * (1.f / 64.f) - mu * mu;
  float yn = (y - mu) * rsqrtf(var + 1e-5f);
  float tg = (yn * gw[(h << 6) + lane] + gbias[(h << 6) + lane]) * bf2f(gb[base + lane]);
  t_o[base + lane] = f2bf(tg);
}

// ---------------------------------------------------------------------------
extern "C" void kernel_launch(void* const* d_in, const int* in_sizes, int n_in,
                              void* d_out, int out_size, void* d_ws, size_t ws_size,
                              hipStream_t stream) {
  const float* x      = (const float*)d_in[0];
  const float* state  = (const float*)d_in[1];
  const float* ln1_w  = (const float*)d_in[2];
  const float* ln1_b  = (const float*)d_in[3];
  const float* ln2_w  = (const float*)d_in[4];
  const float* ln2_b  = (const float*)d_in[5];
  const float* maa_x  = (const float*)d_in[6];
  const float* maa_k  = (const float*)d_in[8];
  const float* maa_v  = (const float*)d_in[9];
  const float* maa_r  = (const float*)d_in[10];
  const float* maa_g  = (const float*)d_in[11];
  const float* maa_w1 = (const float*)d_in[12];
  const float* maa_w2 = (const float*)d_in[13];
  // decay (14,15,16) dead: w gate never reaches the returned output
  const float* faaaa  = (const float*)d_in[17];
  const float* Wr     = (const float*)d_in[18];
  const float* Wk     = (const float*)d_in[19];
  const float* Wv     = (const float*)d_in[20];
  const float* Wo     = (const float*)d_in[21];
  const float* Wg     = (const float*)d_in[22];
  const float* gn_w   = (const float*)d_in[23];
  const float* gn_b   = (const float*)d_in[24];
  const float* fmk    = (const float*)d_in[25];
  const float* fmr    = (const float*)d_in[26];
  const float* fWk    = (const float*)d_in[27];
  const float* fWr    = (const float*)d_in[28];
  const float* fWv    = (const float*)d_in[29];
  const int*   ip     = (const int*)d_in[30];
  float* out = (float*)d_out;

  char* wsb = (char*)d_ws;
  const size_t MB = 1ull << 20;
  u16* wbf   = (u16*)(wsb + 0 * MB);     // 8 x [2048,2048] bf16 = 64 MB
  u16* w1t   = (u16*)(wsb + 64 * MB);    // [320][2048] bf16 (2 MB alloc, OOB slack)
  u16* w2t   = (u16*)(wsb + 66 * MB);    // [4][2048][64] bf16
  u16* xn    = (u16*)(wsb + 68 * MB);
  u16* sx    = (u16*)(wsb + 72 * MB);
  u16* a1    = (u16*)(wsb + 76 * MB);
  float* xxxf = (float*)(wsb + 80 * MB); // [1024,320] f32
  u16* xxx   = (u16*)(wsb + 82 * MB);    // [1024,320] bf16
  u16* xk    = (u16*)(wsb + 83 * MB);
  u16* xv    = (u16*)(wsb + 87 * MB);
  u16* xr    = (u16*)(wsb + 91 * MB);
  u16* xg    = (u16*)(wsb + 95 * MB);
  u16* rb    = (u16*)(wsb + 99 * MB);
  u16* kb    = (u16*)(wsb + 103 * MB);
  u16* vbf   = (u16*)(wsb + 107 * MB);
  u16* gbf   = (u16*)(wsb + 111 * MB);
  u16* tb    = (u16*)(wsb + 115 * MB);
  float* x1  = (float*)(wsb + 119 * MB); // f32 8 MB
  u16* xk2   = (u16*)(wsb + 127 * MB);
  u16* xr2   = (u16*)(wsb + 131 * MB);
  u16* rr    = (u16*)(wsb + 135 * MB);
  u16* kkb   = (u16*)(wsb + 139 * MB);   // end 143 MB (ws ~2.2 GB)

  const size_t WSQ = 4194304;            // elements per 2048x2048 weight
  u16* bWr = wbf + 0 * WSQ; u16* bWk = wbf + 1 * WSQ; u16* bWv = wbf + 2 * WSQ;
  u16* bWg = wbf + 3 * WSQ; u16* bWo = wbf + 4 * WSQ; u16* bfWr = wbf + 5 * WSQ;
  u16* bfWk = wbf + 6 * WSQ; u16* bfWv = wbf + 7 * WSQ;

  auto mkd = [](const u16* A, const u16* B, void* C, const void* p1,
                const void* p2, const float* pvec, int lda, int ldb, int ldc,
                int N, int K, int k0, int epf) {
    GemmDesc d; d.A = A; d.B = B; d.C = C; d.p1 = p1; d.p2 = p2; d.pvec = pvec;
    d.lda = lda; d.ldb = ldb; d.ldc = ldc; d.N = N; d.K = K; d.k0 = k0; d.ep = epf;
    return d;
  };

  // 0) weight conversion (every call; deterministic)
  {
    CvtArgs ca; ca.s[0] = Wr; ca.s[1] = Wk; ca.s[2] = Wv; ca.s[3] = Wg;
    ca.s[4] = Wo; ca.s[5] = fWr; ca.s[6] = fWk; ca.s[7] = fWv;
    k_cvt8<<<16384, 256, 0, stream>>>(ca, wbf);
    k_cvtT<<<4608, 256, 0, stream>>>(maa_w1, maa_w2, w1t, w2t);
  }

  // 1) LN1 + shift (+ zero xxxf)
  k_ln_mix1<<<1024, 256, 0, stream>>>(x, state, ip, ln1_w, ln1_b, maa_x, xn, sx, a1, xxxf);

  // 2) xxxf += a1 @ w1t^T  (split-K 4, atomic f32)
  {
    GemmBatch g{}; g.bpg = 8 * 3;
    for (int j = 0; j < 4; ++j)
      g.g[j] = mkd(a1, w1t, xxxf, nullptr, nullptr, nullptr, 2048, 2048, 320,
                   320, 512, j * 512, EP_AT);
    k_gemm<<<96, 256, 0, stream>>>(g);
  }
  k_tanhpack<<<1280, 256, 0, stream>>>(xxxf, xxx);

  // 3) LoRA mix j=1..4: x* = xn + sx*(maa_* + xxx_j @ w2t_j^T)
  {
    GemmBatch g{}; g.bpg = 8 * 16;
    const float* mv[4] = {maa_k, maa_v, maa_r, maa_g};
    u16* tv[4] = {xk, xv, xr, xg};
    for (int j = 1; j <= 4; ++j)
      g.g[j - 1] = mkd(xxx + j * 64, w2t + (size_t)(j - 1) * 131072, tv[j - 1],
                       xn, sx, mv[j - 1], 320, 64, 2048, 2048, 64, 0, EP_MIX);
    k_gemm<<<512, 256, 0, stream>>>(g);
  }

  // 4) r,k,v,g big GEMMs (batched, 512 blocks)
  {
    GemmBatch g{}; g.bpg = 8 * 16;
    g.g[0] = mkd(xr, bWr, rb,  nullptr, nullptr, nullptr, 2048, 2048, 2048, 2048, 2048, 0, EP_STORE);
    g.g[1] = mkd(xk, bWk, kb,  nullptr, nullptr, nullptr, 2048, 2048, 2048, 2048, 2048, 0, EP_STORE);
    g.g[2] = mkd(xv, bWv, vbf, nullptr, nullptr, nullptr, 2048, 2048, 2048, 2048, 2048, 0, EP_STORE);
    g.g[3] = mkd(xg, bWg, gbf, nullptr, nullptr, nullptr, 2048, 2048, 2048, 2048, 2048, 0, EP_SILU);
    k_gemm<<<512, 256, 0, stream>>>(g);
  }

  // 5) WKV + groupnorm + gate (+ x1 = x)
  k_wkv<<<8192, 256, 0, stream>>>(rb, kb, vbf, gbf, state, ip, faaaa, gn_w, gn_b, tb, x, x1);

  // 6) x1 += tb @ Wo^T  (split-K 2, atomic)
  {
    GemmBatch g{}; g.bpg = 8 * 16;
    g.g[0] = mkd(tb, bWo, x1, nullptr, nullptr, nullptr, 2048, 2048, 2048, 2048, 1024, 0,    EP_AT);
    g.g[1] = mkd(tb, bWo, x1, nullptr, nullptr, nullptr, 2048, 2048, 2048, 2048, 1024, 1024, EP_AT);
    k_gemm<<<256, 256, 0, stream>>>(g);
  }

  // 7) LN2 + ffn shift (+ out = x1)
  k_ln_mix2<<<1024, 256, 0, stream>>>(x1, state, ip, ln2_w, ln2_b, fmk, fmr, xk2, xr2, out);

  // 8) rr = sigmoid(xr2@fWr^T); kk = relu(xk2@fWk^T)^2
  {
    GemmBatch g{}; g.bpg = 8 * 16;
    g.g[0] = mkd(xr2, bfWr, rr,  nullptr, nullptr, nullptr, 2048, 2048, 2048, 2048, 2048, 0, EP_SIG);
    g.g[1] = mkd(xk2, bfWk, kkb, nullptr, nullptr, nullptr, 2048, 2048, 2048, 2048, 2048, 0, EP_RELU2);
    k_gemm<<<256, 256, 0, stream>>>(g);
  }

  // 9) out += rr * (kk @ fWv^T)  (split-K 2, atomic, rr distributes)
  {
    GemmBatch g{}; g.bpg = 8 * 16;
    g.g[0] = mkd(kkb, bfWv, out, nullptr, rr, nullptr, 2048, 2048, 2048, 2048, 1024, 0,    EP_ATSC);
    g.g[1] = mkd(kkb, bfWv, out, nullptr, rr, nullptr, 2048, 2048, 2048, 2048, 1024, 1024, EP_ATSC);
    k_gemm<<<256, 256, 0, stream>>>(g);
  }
}